// Round 7
// baseline (834.333 us; speedup 1.0000x reference)
//
#include <hip/hip_runtime.h>

typedef unsigned short u16t;
typedef unsigned int   u32t;
typedef __attribute__((ext_vector_type(8))) __bf16          bf16x8;
typedef __attribute__((ext_vector_type(8))) unsigned short  u16x8;
typedef __attribute__((ext_vector_type(4))) unsigned short  u16x4;
typedef __attribute__((ext_vector_type(4))) float           floatx4;

// f32 -> bf16 round-to-nearest-even (no NaN inputs in this problem)
__device__ __forceinline__ u16t f2b(float f){
  u32t u = __builtin_bit_cast(u32t, f);
  u += 0x7fffu + ((u >> 16) & 1u);
  return (u16t)(u >> 16);
}
__device__ __forceinline__ float b2f(u16t h){
  return __builtin_bit_cast(float, (u32t)h << 16);
}
// async global->LDS, 16B per lane. lds ptr must be wave-uniform (HW adds lane*16).
__device__ __forceinline__ void async16(const void* g, void* l){
  __builtin_amdgcn_global_load_lds((__attribute__((address_space(1))) void*)g,
                                   (__attribute__((address_space(3))) void*)l, 16, 0, 0);
}
__device__ __forceinline__ bf16x8 ldfrag(const u16t* p){
  return __builtin_bit_cast(bf16x8, *(const u16x8*)p);
}

// ---------------------------------------------------------------- cvt f32->bf16
__global__ __launch_bounds__(256)
void cvt_f32_bf16(const float* __restrict__ in, u16t* __restrict__ out, int n4){
  typedef __attribute__((ext_vector_type(4))) float f32x4;
  const f32x4* in4 = (const f32x4*)in;
  int stride = gridDim.x * blockDim.x;
  for (int i = blockIdx.x * blockDim.x + threadIdx.x; i < n4; i += stride){
    f32x4 v = in4[i];
    u16x4 o; o[0]=f2b(v[0]); o[1]=f2b(v[1]); o[2]=f2b(v[2]); o[3]=f2b(v[3]);
    *(u16x4*)(out + (size_t)i * 4) = o;
  }
}

// ---------------------------------------------------------------- GEMM C = A * B^T
// 256x256 tile, BK=64, 8 waves (2M x 4N), 128 KiB double-buffered LDS.
// Round-2 proven schedule (QKV 245 us): 4 phases per K-tile, each phase = one
// C-quadrant's 16 MFMAs with only that quadrant's new fragments ds_read in the
// same phase (12/8/4/0), 1 half-tile global_load_lds prefetch per phase,
// counted vmcnt(6) once per K-tile (never 0 mid-loop).
// Staging windows: A0,B0 regions last read @ph1; A1 @ph2; B1 @ph3. Stage into
// cur buf: ph2 <- (t+2).A0, ph3 <- (t+2).A1, ph4 <- (t+2).B0; (t+1).B1 goes to
// the other buffer @ph1. vmcnt(6) @ph4 => tile t+1 fully landed.
// LDS XOR-swizzle: linear LDS dest + inverse-swizzled per-lane GLOBAL source,
// same involution applied on ds_read (rule #21).
#define MFMA16 __builtin_amdgcn_mfma_f32_16x16x32_bf16
template<int OUT_BF16>
__global__ __launch_bounds__(512, 2)
void gemm256(const u16t* __restrict__ A, const u16t* __restrict__ B,
             void* __restrict__ Cv, int M, int N, int K)
{
  (void)M;
  __shared__ u16t smem[65536];              // bytes: A [0,64K), B [64K,128K)
  const int tid  = threadIdx.x;
  const int w    = tid >> 6, lane = tid & 63;
  const int lrow = lane & 15, quad = lane >> 4;
  const int wr   = w >> 2,  wc = w & 3;

  // bijective XCD-aware workgroup swizzle (m204)
  const int nwg  = (int)(gridDim.x * gridDim.y);
  const int flat = (int)(blockIdx.y * gridDim.x + blockIdx.x);
  const int q8 = nwg >> 3, r8 = nwg & 7, xcd = flat & 7, idx = flat >> 3;
  const int wg = (xcd < r8 ? xcd * (q8 + 1) : r8 * (q8 + 1) + (xcd - r8) * q8) + idx;
  const int m0 = (wg / (int)gridDim.x) * 256;
  const int n0 = (wg % (int)gridDim.x) * 256;

  // ---- staging: linear LDS dest (wave-uniform base, HW adds lane*16),
  //      pre-swizzled per-lane global source
  const int srow = lane >> 3;                    // 0..7  (row within 8-row strip)
  const int scol = ((lane & 7) ^ srow) * 8;      // inverse-swizzled k element
  const u16t* gA = A + (size_t)(m0 + w * 8 + srow) * K + scol;
  const u16t* gB = B + (size_t)(n0 + w * 8 + srow) * K + scol;
  char* const ldsA = (char*)smem + w * 1024;
  char* const ldsB = (char*)smem + 65536 + w * 1024;
#define STA(h, i, buf, kt) async16(gA + (size_t)((h)*128 + (i)*64) * K + (kt)*64, \
                                   ldsA + (buf)*32768 + ((h)*2+(i))*8192)
#define STB(h, i, buf, kt) async16(gB + (size_t)((h)*128 + (i)*64) * K + (kt)*64, \
                                   ldsB + (buf)*32768 + ((h)*2+(i))*8192)

  // ---- swizzled fragment-read byte offsets
  const char* const sbb = (const char*)smem;
  const int c0   = ((quad ^ (lrow & 7)) * 16);       // ks=0 chunk; ks=1 = c0^64
  const int aoff = (wr * 128 + lrow) * 128;          // + mi*2048 + chunk
  const int boff = 65536 + (wc * 64 + lrow) * 128;   // + ni*2048 + chunk

  floatx4 acc[8][4] = {};
  bf16x8 A0f[4][2], A1f[4][2], Bf0[2][2], Bf1[2][2];
  const int NT = K >> 6;

  // ---- prologue: tile0 {A0,A1,B0,B1} -> buf0, tile1 {A0,A1,B0} -> buf1
  STA(0,0,0,0); STA(0,1,0,0); STA(1,0,0,0); STA(1,1,0,0);
  STB(0,0,0,0); STB(0,1,0,0); STB(1,0,0,0); STB(1,1,0,0);
  STA(0,0,1,1); STA(0,1,1,1); STA(1,0,1,1); STA(1,1,1,1);
  STB(0,0,1,1); STB(0,1,1,1);
  asm volatile("s_waitcnt vmcnt(6)" ::: "memory");   // tile0 fully landed
  __builtin_amdgcn_sched_barrier(0);
  __builtin_amdgcn_s_barrier();

  for (int t = 0; t < NT; ++t){
    const int bsel = t & 1, nb = bsel ^ 1;
    const int bo = bsel * 32768;

    // ---------- phase 1: read A0 + B0 (12 reads); MFMA quadrant (A0,B0);
    //            stage (t+1).B1 -> other buf
#pragma unroll
    for (int mi = 0; mi < 4; ++mi){
      A0f[mi][0] = ldfrag((const u16t*)(sbb + bo + aoff + mi * 2048 + c0));
      A0f[mi][1] = ldfrag((const u16t*)(sbb + bo + aoff + mi * 2048 + (c0 ^ 64)));
    }
#pragma unroll
    for (int ni = 0; ni < 2; ++ni){
      Bf0[ni][0] = ldfrag((const u16t*)(sbb + bo + boff + ni * 2048 + c0));
      Bf0[ni][1] = ldfrag((const u16t*)(sbb + bo + boff + ni * 2048 + (c0 ^ 64)));
    }
    if (t + 1 < NT){ STB(1,0,nb,t+1); STB(1,1,nb,t+1); }
    __builtin_amdgcn_s_barrier();
    asm volatile("s_waitcnt lgkmcnt(0)" ::: "memory");
    __builtin_amdgcn_sched_barrier(0);
    __builtin_amdgcn_s_setprio(1);
#pragma unroll
    for (int mi = 0; mi < 4; ++mi)
#pragma unroll
      for (int ni = 0; ni < 2; ++ni){
        acc[mi][ni] = MFMA16(A0f[mi][0], Bf0[ni][0], acc[mi][ni], 0, 0, 0);
        acc[mi][ni] = MFMA16(A0f[mi][1], Bf0[ni][1], acc[mi][ni], 0, 0, 0);
      }
    __builtin_amdgcn_s_setprio(0);
    __builtin_amdgcn_sched_barrier(0);
    __builtin_amdgcn_s_barrier();

    // ---------- phase 2: read A1 (8 reads); MFMA quadrant (A1,B0);
    //            stage (t+2).A0 -> cur buf (A0 region free after ph1)
#pragma unroll
    for (int mi = 0; mi < 4; ++mi){
      A1f[mi][0] = ldfrag((const u16t*)(sbb + bo + aoff + (4 + mi) * 2048 + c0));
      A1f[mi][1] = ldfrag((const u16t*)(sbb + bo + aoff + (4 + mi) * 2048 + (c0 ^ 64)));
    }
    if (t + 2 < NT){ STA(0,0,bsel,t+2); STA(0,1,bsel,t+2); }
    __builtin_amdgcn_s_barrier();
    asm volatile("s_waitcnt lgkmcnt(0)" ::: "memory");
    __builtin_amdgcn_sched_barrier(0);
    __builtin_amdgcn_s_setprio(1);
#pragma unroll
    for (int mi = 0; mi < 4; ++mi)
#pragma unroll
      for (int ni = 0; ni < 2; ++ni){
        acc[4+mi][ni] = MFMA16(A1f[mi][0], Bf0[ni][0], acc[4+mi][ni], 0, 0, 0);
        acc[4+mi][ni] = MFMA16(A1f[mi][1], Bf0[ni][1], acc[4+mi][ni], 0, 0, 0);
      }
    __builtin_amdgcn_s_setprio(0);
    __builtin_amdgcn_sched_barrier(0);
    __builtin_amdgcn_s_barrier();

    // ---------- phase 3: read B1 (4 reads); MFMA quadrant (A0,B1);
    //            stage (t+2).A1 -> cur buf (A1 region free after ph2)
#pragma unroll
    for (int ni = 0; ni < 2; ++ni){
      Bf1[ni][0] = ldfrag((const u16t*)(sbb + bo + boff + (2 + ni) * 2048 + c0));
      Bf1[ni][1] = ldfrag((const u16t*)(sbb + bo + boff + (2 + ni) * 2048 + (c0 ^ 64)));
    }
    if (t + 2 < NT){ STA(1,0,bsel,t+2); STA(1,1,bsel,t+2); }
    __builtin_amdgcn_s_barrier();
    asm volatile("s_waitcnt lgkmcnt(0)" ::: "memory");
    __builtin_amdgcn_sched_barrier(0);
    __builtin_amdgcn_s_setprio(1);
#pragma unroll
    for (int mi = 0; mi < 4; ++mi)
#pragma unroll
      for (int ni = 0; ni < 2; ++ni){
        acc[mi][2+ni] = MFMA16(A0f[mi][0], Bf1[ni][0], acc[mi][2+ni], 0, 0, 0);
        acc[mi][2+ni] = MFMA16(A0f[mi][1], Bf1[ni][1], acc[mi][2+ni], 0, 0, 0);
      }
    __builtin_amdgcn_s_setprio(0);
    __builtin_amdgcn_sched_barrier(0);
    __builtin_amdgcn_s_barrier();

    // ---------- phase 4: no reads; MFMA quadrant (A1,B1);
    //            stage (t+2).B0 -> cur buf (B0 region free after ph1); vmcnt
    if (t + 2 < NT){ STB(0,0,bsel,t+2); STB(0,1,bsel,t+2); }
    __builtin_amdgcn_s_barrier();
    __builtin_amdgcn_s_setprio(1);
#pragma unroll
    for (int mi = 0; mi < 4; ++mi)
#pragma unroll
      for (int ni = 0; ni < 2; ++ni){
        acc[4+mi][2+ni] = MFMA16(A1f[mi][0], Bf1[ni][0], acc[4+mi][2+ni], 0, 0, 0);
        acc[4+mi][2+ni] = MFMA16(A1f[mi][1], Bf1[ni][1], acc[4+mi][2+ni], 0, 0, 0);
      }
    __builtin_amdgcn_s_setprio(0);
    __builtin_amdgcn_sched_barrier(0);
    if (t + 2 < NT) asm volatile("s_waitcnt vmcnt(6)" ::: "memory");
    else            asm volatile("s_waitcnt vmcnt(0)" ::: "memory");
    __builtin_amdgcn_sched_barrier(0);
    __builtin_amdgcn_s_barrier();
  }

  // ---- epilogue: C/D layout col=lane&15, row=quad*4+reg (verified mapping)
#pragma unroll
  for (int mi = 0; mi < 8; ++mi)
#pragma unroll
    for (int ni = 0; ni < 4; ++ni)
#pragma unroll
      for (int r = 0; r < 4; ++r){
        int row = m0 + wr * 128 + mi * 16 + quad * 4 + r;
        int col = n0 + wc * 64 + ni * 16 + lrow;
        float v = acc[mi][ni][r];
        if (OUT_BF16) ((u16t*)Cv)[(size_t)row * N + col] = f2b(v);
        else          ((float*)Cv)[(size_t)row * N + col] = v;
      }
#undef STA
#undef STB
}

// ---------------------------------------------------------------- RoPE + layout
__global__ __launch_bounds__(256)
void rope_qk(const u16t* __restrict__ qkvb, const float* __restrict__ cosp,
             const float* __restrict__ sinp, u16t* __restrict__ qr, u16t* __restrict__ kr)
{
  const int row = blockIdx.x;            // b*2048 + t
  const int b = row >> 11, t = row & 2047;
  const u16t* src = qkvb + (size_t)row * 6144;
  for (int p = threadIdx.x; p < 2560; p += 256){
    u32t both = *(const u32t*)(src + 2 * p);
    float t0 = b2f((u16t)(both & 0xffff));
    float t1 = b2f((u16t)(both >> 16));
    int j = p & 63;
    float c = cosp[t * 64 + j], s = sinp[t * 64 + j];
    float o0 = t0 * c - t1 * s;
    float o1 = t0 * s + t1 * c;
    u32t packed = (u32t)f2b(o0) | ((u32t)f2b(o1) << 16);
    if (p < 2048){
      int h = p >> 6;
      *(u32t*)(qr + (((size_t)(b * 32 + h) * 2048 + t) * 128 + 2 * j)) = packed;
    } else {
      int kh = (p - 2048) >> 6;
      *(u32t*)(kr + (((size_t)(b * 8 + kh) * 2048 + t) * 128 + 2 * j)) = packed;
    }
  }
}

// ---------------------------------------------------------------- V transpose
__global__ __launch_bounds__(256)
void vtrans(const u16t* __restrict__ qkvb, u16t* __restrict__ vt)
{
  __shared__ u16t sV[64 * 128];
  const int tid = threadIdx.x;
  const int blk = blockIdx.x;                 // (b, kvh, tile)
  const int tile = blk & 31, kvh = (blk >> 5) & 7, b = blk >> 8;
  const int t0 = tile * 64;
  const size_t srcbase = (size_t)(b * 2048 + t0) * 6144 + 5120 + kvh * 128;
#pragma unroll
  for (int it = 0; it < 4; ++it){
    int task = it * 256 + tid;
    int rrow = task >> 4, cb = task & 15;
    *(u16x8*)&sV[rrow * 128 + cb * 8] =
        *(const u16x8*)(qkvb + srcbase + (size_t)rrow * 6144 + cb * 8);
  }
  __syncthreads();
  const size_t dstbase = (size_t)((b * 8 + kvh) * 128) * 2048 + t0;
#pragma unroll
  for (int it = 0; it < 4; ++it){
    int task = it * 256 + tid;
    int tc = task & 7, d = task >> 3;
    u16x8 v;
#pragma unroll
    for (int j = 0; j < 8; ++j) v[j] = sV[(tc * 8 + j) * 128 + d];
    *(u16x8*)(vt + dstbase + (size_t)d * 2048 + tc * 8) = v;
  }
}

// ---------------------------------------------------------------- flash attention v2
// Q (B,32,T,128), K (B,8,T,128), Vt (B,8,128,T) bf16 -> Y (B,T,32*128) bf16.
// 128 q-rows/block, 4 waves x 32 rows (2 x 16-row subtiles per wave): each
// bk/bv fragment read feeds TWO MFMAs (register reuse across subtiles) ->
// per-q-row DS traffic ~2x lower than the 64-row version (attn is DS-bound).
// Q in registers (global, once). K double-buffered; V SINGLE-buffered (its
// HBM latency hides under QK+softmax). Counted-vmcnt ladder, never drained
// mid-loop: issue V(t)+K(t+1) -> vmcnt(8) = K(t) landed -> QK -> softmax ->
// vmcnt(4) = V(t) landed (K(t+1) still in flight) -> PV -> end barrier.
// LDS: K dbuf 2x16K + V 16K + P 18K = 66 KB -> 2 blocks/CU, 8 waves/CU at
// ~150 VGPR (2 waves/SIMD). This is the round-4 DS-cut WITHOUT its occupancy
// loss (round-4: 64-82 KB + sQ => 4 waves/CU => latency-bound at 10% MfmaUtil).
__global__ __launch_bounds__(256)
void attn_fwd(const u16t* __restrict__ Qg, const u16t* __restrict__ Kg,
              const u16t* __restrict__ Vt, u16t* __restrict__ Y)
{
  __shared__ u16t smem[33792];         // 66 KB
  // u16 units: K buf0 [0,8192) buf1 [8192,16384); V [16384,24576); P [24576,33792)
  u16t* sV = smem + 16384;             // [kvc:8][d:128] 16B chunks
  u16t* sP = smem + 24576;             // [q:128] stride 72 u16

  const int tid  = threadIdx.x;
  const int wave = tid >> 6, lane = tid & 63;
  const int lrow = lane & 15, quad = lane >> 4;
  const int qt = 15 - (int)blockIdx.y;     // longest blocks dispatch first
  const int q0 = qt * 128;
  const int bh = blockIdx.x;
  const int b = bh >> 5, h = bh & 31, kvh = h >> 2;
  const float qscale = 0.088388347648318447f * 1.4426950408889634f; // 1/sqrt(128)*log2(e)

  // Q fragments straight from global (once per block), verified round 5
  bf16x8 aq[2][4];
  const size_t qbase = ((size_t)bh * 2048 + q0 + wave * 32) * 128;
#pragma unroll
  for (int qs = 0; qs < 2; ++qs)
#pragma unroll
    for (int kk = 0; kk < 4; ++kk)
      aq[qs][kk] = ldfrag(Qg + qbase + (size_t)(qs * 16 + lrow) * 128 + (kk * 4 + quad) * 8);

  const size_t kbase = ((size_t)(b * 8 + kvh) * 2048) * 128;
  const size_t vbase = ((size_t)(b * 8 + kvh) * 128) * 2048;

  // stage K tile kt_ into K buffer bs_ (4 async16 per wave)
#define STAGEK(kt_, bs_) {                                                      \
    const int k0_ = (kt_) * 64;                                                 \
    char* dK = (char*)smem + (bs_) * 16384;                                     \
    _Pragma("unroll")                                                           \
    for (int r = 0; r < 4; ++r){                                                \
      const int dc = r * 4 + wave;                                              \
      async16(Kg + kbase + (size_t)(k0_ + lane) * 128 + dc * 8, dK + dc * 1024);\
    } }
  // stage V tile kt_ into the single V buffer (4 async16 per wave)
#define STAGEV(kt_) {                                                           \
    const int k0_ = (kt_) * 64;                                                 \
    char* dV = (char*)smem + 32768;                                             \
    _Pragma("unroll")                                                           \
    for (int r = 0; r < 4; ++r){                                                \
      const int kvc = r * 2 + (wave >> 1);                                      \
      const int dd  = (wave & 1) * 64 + lane;                                   \
      async16(Vt + vbase + (size_t)dd * 2048 + k0_ + kvc * 8,                   \
              dV + kvc * 2048 + (wave & 1) * 1024);                             \
    } }

  float mi[2][4], li[2][4];
#pragma unroll
  for (int qs = 0; qs < 2; ++qs)
#pragma unroll
    for (int r = 0; r < 4; ++r){ mi[qs][r] = -1e30f; li[qs][r] = 0.f; }
  floatx4 o[2][8] = {};
  const int ktiles = 2 * qt + 2;

  STAGEK(0, 0);                        // prologue

  for (int kt = 0; kt < ktiles; ++kt){
    const int bsel = kt & 1;
    const int k0 = kt * 64;
    STAGEV(kt);                        // V(t): consumed at PV, latency hidden
    if (kt + 1 < ktiles){
      STAGEK(kt + 1, bsel ^ 1);        // prefetch next K into other buffer
      asm volatile("s_waitcnt vmcnt(8)" ::: "memory");   // K(t) landed
    } else {
      asm volatile("s_waitcnt vmcnt(4)" ::: "memory");   // K(t) landed
    }
    __builtin_amdgcn_sched_barrier(0);
    __builtin_amdgcn_s_barrier();      // all waves' K(t) visible

    const u16t* cK = smem + bsel * 8192;

    // S = Q K^T   (bk register-reused across both q-subtiles)
    floatx4 s[2][4] = {};
    __builtin_amdgcn_s_setprio(1);
#pragma unroll
    for (int kk = 0; kk < 4; ++kk){
#pragma unroll
      for (int nt = 0; nt < 4; ++nt){
        bf16x8 bk = ldfrag(&cK[((kk * 4 + quad) * 64 + nt * 16 + lrow) * 8]);
        s[0][nt] = __builtin_amdgcn_mfma_f32_16x16x32_bf16(aq[0][kk], bk, s[0][nt], 0, 0, 0);
        s[1][nt] = __builtin_amdgcn_mfma_f32_16x16x32_bf16(aq[1][kk], bk, s[1][nt], 0, 0, 0);
      }
    }
    __builtin_amdgcn_s_setprio(0);

    // softmax per q-subtile
#pragma unroll
    for (int qs = 0; qs < 2; ++qs){
      float tt[4][4];
#pragma unroll
      for (int nt = 0; nt < 4; ++nt)
#pragma unroll
        for (int r = 0; r < 4; ++r)
          tt[nt][r] = s[qs][nt][r] * qscale;
      const int qrb = q0 + wave * 32 + qs * 16 + quad * 4;
      if (kt >= ktiles - 2){   // causal mask only intersects the last two kv tiles
#pragma unroll
        for (int nt = 0; nt < 4; ++nt){
          int kc = k0 + nt * 16 + lrow;
#pragma unroll
          for (int r = 0; r < 4; ++r)
            if (kc > qrb + r) tt[nt][r] = -1e30f;
        }
      }
      float rmax[4];
#pragma unroll
      for (int r = 0; r < 4; ++r)
        rmax[r] = fmaxf(fmaxf(tt[0][r], tt[1][r]), fmaxf(tt[2][r], tt[3][r]));
#pragma unroll
      for (int off = 1; off < 16; off <<= 1){
#pragma unroll
        for (int r = 0; r < 4; ++r)
          rmax[r] = fmaxf(rmax[r], __shfl_xor(rmax[r], off, 64));
      }
      float alpha[4];
#pragma unroll
      for (int r = 0; r < 4; ++r){
        float mn = fmaxf(mi[qs][r], rmax[r]);
        alpha[r] = __builtin_amdgcn_exp2f(mi[qs][r] - mn);
        mi[qs][r] = mn;
      }
      float lsum[4] = {0.f, 0.f, 0.f, 0.f};
#pragma unroll
      for (int nt = 0; nt < 4; ++nt)
#pragma unroll
        for (int r = 0; r < 4; ++r){
          float e = __builtin_amdgcn_exp2f(tt[nt][r] - mi[qs][r]);
          lsum[r] += e;
          sP[(wave * 32 + qs * 16 + quad * 4 + r) * 72 + nt * 16 + lrow] = f2b(e);
        }
#pragma unroll
      for (int off = 1; off < 16; off <<= 1){
#pragma unroll
        for (int r = 0; r < 4; ++r)
          lsum[r] += __shfl_xor(lsum[r], off, 64);
      }
#pragma unroll
      for (int r = 0; r < 4; ++r) li[qs][r] = li[qs][r] * alpha[r] + lsum[r];
#pragma unroll
      for (int nt = 0; nt < 8; ++nt){
        o[qs][nt][0] *= alpha[0]; o[qs][nt][1] *= alpha[1];
        o[qs][nt][2] *= alpha[2]; o[qs][nt][3] *= alpha[3];
      }
    }

    // V(t) landed? (own 4 V loads older than the 4 in-flight K(t+1) loads)
    if (kt + 1 < ktiles) asm volatile("s_waitcnt vmcnt(4)" ::: "memory");
    else                 asm volatile("s_waitcnt vmcnt(0)" ::: "memory");
    __builtin_amdgcn_sched_barrier(0);
    __builtin_amdgcn_s_barrier();      // cross-wave V visibility
    // (sP: each wave reads only its own rows -> same-wave DS ordering, no barrier)

    // O += P V   (bv register-reused across both q-subtiles)
    __builtin_amdgcn_s_setprio(1);
#pragma unroll
    for (int kk = 0; kk < 2; ++kk){
      bf16x8 ap0 = ldfrag(&sP[(wave * 32 + lrow) * 72 + kk * 32 + quad * 8]);
      bf16x8 ap1 = ldfrag(&sP[(wave * 32 + 16 + lrow) * 72 + kk * 32 + quad * 8]);
#pragma unroll
      for (int nt = 0; nt < 8; ++nt){
        bf16x8 bv = ldfrag(&sV[((kk * 4 + quad) * 128 + nt * 16 + lrow) * 8]);
        o[0][nt] = __builtin_amdgcn_mfma_f32_16x16x32_bf16(ap0, bv, o[0][nt], 0, 0, 0);
        o[1][nt] = __builtin_amdgcn_mfma_f32_16x16x32_bf16(ap1, bv, o[1][nt], 0, 0, 0);
      }
    }
    __builtin_amdgcn_s_setprio(0);
    __builtin_amdgcn_sched_barrier(0);
    __builtin_amdgcn_s_barrier();      // V + K[bsel] reads done; safe to restage
  }
#undef STAGEK
#undef STAGEV

  // epilogue: O/l -> Y (B,T,4096)
#pragma unroll
  for (int qs = 0; qs < 2; ++qs)
#pragma unroll
    for (int r = 0; r < 4; ++r){
      int t = q0 + wave * 32 + qs * 16 + quad * 4 + r;
      float inv = 1.0f / li[qs][r];
      size_t ybase = ((size_t)(b * 2048 + t)) * 4096 + h * 128;
#pragma unroll
      for (int nt = 0; nt < 8; ++nt)
        Y[ybase + nt * 16 + lrow] = f2b(o[qs][nt][r] * inv);
    }
}

// ---------------------------------------------------------------- launch
extern "C" void kernel_launch(void* const* d_in, const int* in_sizes, int n_in,
                              void* d_out, int out_size, void* d_ws, size_t ws_size,
                              hipStream_t stream)
{
  (void)in_sizes; (void)n_in; (void)out_size; (void)ws_size;
  const float* x    = (const float*)d_in[0];   // (2,2048,4096)
  const float* fc   = (const float*)d_in[1];   // (2048,64)
  const float* fs   = (const float*)d_in[2];   // (2048,64)
  const float* wqkv = (const float*)d_in[3];   // (6144,4096)
  const float* wo   = (const float*)d_in[4];   // (4096,4096)
  float* out = (float*)d_out;                  // (2,2048,4096) f32

  char* ws = (char*)d_ws;
  u16t* xb    = (u16t*)(ws);                    // 32 MiB (reused as yb after gemm1)
  u16t* wqkvb = (u16t*)(ws + 33554432);         // 48 MiB
  u16t* wob   = (u16t*)(ws + 83886080);         // 32 MiB
  u16t* qkvb  = (u16t*)(ws + 117440512);        // 48 MiB
  u16t* qr    = (u16t*)(ws + 167772160);        // 32 MiB
  u16t* kr    = (u16t*)(ws + 201326592);        //  8 MiB
  u16t* vt    = (u16t*)(ws + 209715200);        //  8 MiB  (total 208 MiB)
  u16t* yb    = xb;                             // alias: x dead after gemm1

  cvt_f32_bf16<<<4096, 256, 0, stream>>>(x,    xb,    16777216 / 4);
  cvt_f32_bf16<<<4096, 256, 0, stream>>>(wqkv, wqkvb, 25165824 / 4);
  cvt_f32_bf16<<<4096, 256, 0, stream>>>(wo,   wob,   16777216 / 4);
  gemm256<1><<<dim3(24, 16), 512, 0, stream>>>(xb, wqkvb, qkvb, 4096, 6144, 4096);
  rope_qk<<<4096, 256, 0, stream>>>(qkvb, fc, fs, qr, kr);
  vtrans<<<512, 256, 0, stream>>>(qkvb, vt);
  attn_fwd<<<dim3(64, 16), 256, 0, stream>>>(qr, kr, vt, yb);
  gemm256<0><<<dim3(16, 16), 512, 0, stream>>>(yb, wob, out, 4096, 4096, 4096);
}

// Round 8
// 793.218 us; speedup vs baseline: 1.0518x; 1.0518x over previous
//
#include <hip/hip_runtime.h>

typedef unsigned short u16t;
typedef unsigned int   u32t;
typedef __attribute__((ext_vector_type(8))) __bf16          bf16x8;
typedef __attribute__((ext_vector_type(8))) unsigned short  u16x8;
typedef __attribute__((ext_vector_type(4))) unsigned short  u16x4;
typedef __attribute__((ext_vector_type(4))) float           floatx4;

// f32 -> bf16 round-to-nearest-even (no NaN inputs in this problem)
__device__ __forceinline__ u16t f2b(float f){
  u32t u = __builtin_bit_cast(u32t, f);
  u += 0x7fffu + ((u >> 16) & 1u);
  return (u16t)(u >> 16);
}
__device__ __forceinline__ float b2f(u16t h){
  return __builtin_bit_cast(float, (u32t)h << 16);
}
// packed f32x2 -> bf16x2 (RNE, single instruction; same rounding as f2b)
__device__ __forceinline__ u32t cvtpk(float lo, float hi){
  u32t r;
  asm("v_cvt_pk_bf16_f32 %0, %1, %2" : "=v"(r) : "v"(lo), "v"(hi));
  return r;
}
// async global->LDS, 16B per lane. lds ptr must be wave-uniform (HW adds lane*16).
__device__ __forceinline__ void async16(const void* g, void* l){
  __builtin_amdgcn_global_load_lds((__attribute__((address_space(1))) void*)g,
                                   (__attribute__((address_space(3))) void*)l, 16, 0, 0);
}
__device__ __forceinline__ bf16x8 ldfrag(const u16t* p){
  return __builtin_bit_cast(bf16x8, *(const u16x8*)p);
}

// ---------------------------------------------------------------- cvt f32->bf16
__global__ __launch_bounds__(256)
void cvt_f32_bf16(const float* __restrict__ in, u16t* __restrict__ out, int n4){
  typedef __attribute__((ext_vector_type(4))) float f32x4;
  const f32x4* in4 = (const f32x4*)in;
  int stride = gridDim.x * blockDim.x;
  for (int i = blockIdx.x * blockDim.x + threadIdx.x; i < n4; i += stride){
    f32x4 v = in4[i];
    u16x4 o; o[0]=f2b(v[0]); o[1]=f2b(v[1]); o[2]=f2b(v[2]); o[3]=f2b(v[3]);
    *(u16x4*)(out + (size_t)i * 4) = o;
  }
}

// ---------------------------------------------------------------- GEMM C = A * B^T
// 256x256 tile, BK=64, 8 waves (2M x 4N), 128 KiB double-buffered LDS.
// Round-2 proven schedule (QKV 245 us): 4 phases per K-tile, each phase = one
// C-quadrant's 16 MFMAs with only that quadrant's new fragments ds_read in the
// same phase (12/8/4/0), 1 half-tile global_load_lds prefetch per phase,
// counted vmcnt(6) once per K-tile (never 0 mid-loop).
// Staging windows: A0,B0 regions last read @ph1; A1 @ph2; B1 @ph3. Stage into
// cur buf: ph2 <- (t+2).A0, ph3 <- (t+2).A1, ph4 <- (t+2).B0; (t+1).B1 goes to
// the other buffer @ph1. vmcnt(6) @ph4 => tile t+1 fully landed.
// LDS XOR-swizzle: linear LDS dest + inverse-swizzled per-lane GLOBAL source,
// same involution applied on ds_read (rule #21).
#define MFMA16 __builtin_amdgcn_mfma_f32_16x16x32_bf16
template<int OUT_BF16>
__global__ __launch_bounds__(512, 2)
void gemm256(const u16t* __restrict__ A, const u16t* __restrict__ B,
             void* __restrict__ Cv, int M, int N, int K)
{
  (void)M;
  __shared__ u16t smem[65536];              // bytes: A [0,64K), B [64K,128K)
  const int tid  = threadIdx.x;
  const int w    = tid >> 6, lane = tid & 63;
  const int lrow = lane & 15, quad = lane >> 4;
  const int wr   = w >> 2,  wc = w & 3;

  // bijective XCD-aware workgroup swizzle (m204)
  const int nwg  = (int)(gridDim.x * gridDim.y);
  const int flat = (int)(blockIdx.y * gridDim.x + blockIdx.x);
  const int q8 = nwg >> 3, r8 = nwg & 7, xcd = flat & 7, idx = flat >> 3;
  const int wg = (xcd < r8 ? xcd * (q8 + 1) : r8 * (q8 + 1) + (xcd - r8) * q8) + idx;
  const int m0 = (wg / (int)gridDim.x) * 256;
  const int n0 = (wg % (int)gridDim.x) * 256;

  // ---- staging: linear LDS dest (wave-uniform base, HW adds lane*16),
  //      pre-swizzled per-lane global source
  const int srow = lane >> 3;                    // 0..7  (row within 8-row strip)
  const int scol = ((lane & 7) ^ srow) * 8;      // inverse-swizzled k element
  const u16t* gA = A + (size_t)(m0 + w * 8 + srow) * K + scol;
  const u16t* gB = B + (size_t)(n0 + w * 8 + srow) * K + scol;
  char* const ldsA = (char*)smem + w * 1024;
  char* const ldsB = (char*)smem + 65536 + w * 1024;
#define STA(h, i, buf, kt) async16(gA + (size_t)((h)*128 + (i)*64) * K + (kt)*64, \
                                   ldsA + (buf)*32768 + ((h)*2+(i))*8192)
#define STB(h, i, buf, kt) async16(gB + (size_t)((h)*128 + (i)*64) * K + (kt)*64, \
                                   ldsB + (buf)*32768 + ((h)*2+(i))*8192)

  // ---- swizzled fragment-read byte offsets
  const char* const sbb = (const char*)smem;
  const int c0   = ((quad ^ (lrow & 7)) * 16);       // ks=0 chunk; ks=1 = c0^64
  const int aoff = (wr * 128 + lrow) * 128;          // + mi*2048 + chunk
  const int boff = 65536 + (wc * 64 + lrow) * 128;   // + ni*2048 + chunk

  floatx4 acc[8][4] = {};
  bf16x8 A0f[4][2], A1f[4][2], Bf0[2][2], Bf1[2][2];
  const int NT = K >> 6;

  // ---- prologue: tile0 {A0,A1,B0,B1} -> buf0, tile1 {A0,A1,B0} -> buf1
  STA(0,0,0,0); STA(0,1,0,0); STA(1,0,0,0); STA(1,1,0,0);
  STB(0,0,0,0); STB(0,1,0,0); STB(1,0,0,0); STB(1,1,0,0);
  STA(0,0,1,1); STA(0,1,1,1); STA(1,0,1,1); STA(1,1,1,1);
  STB(0,0,1,1); STB(0,1,1,1);
  asm volatile("s_waitcnt vmcnt(6)" ::: "memory");   // tile0 fully landed
  __builtin_amdgcn_sched_barrier(0);
  __builtin_amdgcn_s_barrier();

  for (int t = 0; t < NT; ++t){
    const int bsel = t & 1, nb = bsel ^ 1;
    const int bo = bsel * 32768;

    // ---------- phase 1: read A0 + B0 (12 reads); MFMA quadrant (A0,B0);
    //            stage (t+1).B1 -> other buf
#pragma unroll
    for (int mi = 0; mi < 4; ++mi){
      A0f[mi][0] = ldfrag((const u16t*)(sbb + bo + aoff + mi * 2048 + c0));
      A0f[mi][1] = ldfrag((const u16t*)(sbb + bo + aoff + mi * 2048 + (c0 ^ 64)));
    }
#pragma unroll
    for (int ni = 0; ni < 2; ++ni){
      Bf0[ni][0] = ldfrag((const u16t*)(sbb + bo + boff + ni * 2048 + c0));
      Bf0[ni][1] = ldfrag((const u16t*)(sbb + bo + boff + ni * 2048 + (c0 ^ 64)));
    }
    if (t + 1 < NT){ STB(1,0,nb,t+1); STB(1,1,nb,t+1); }
    __builtin_amdgcn_s_barrier();
    asm volatile("s_waitcnt lgkmcnt(0)" ::: "memory");
    __builtin_amdgcn_sched_barrier(0);
    __builtin_amdgcn_s_setprio(1);
#pragma unroll
    for (int mi = 0; mi < 4; ++mi)
#pragma unroll
      for (int ni = 0; ni < 2; ++ni){
        acc[mi][ni] = MFMA16(A0f[mi][0], Bf0[ni][0], acc[mi][ni], 0, 0, 0);
        acc[mi][ni] = MFMA16(A0f[mi][1], Bf0[ni][1], acc[mi][ni], 0, 0, 0);
      }
    __builtin_amdgcn_s_setprio(0);
    __builtin_amdgcn_sched_barrier(0);
    __builtin_amdgcn_s_barrier();

    // ---------- phase 2: read A1 (8 reads); MFMA quadrant (A1,B0);
    //            stage (t+2).A0 -> cur buf (A0 region free after ph1)
#pragma unroll
    for (int mi = 0; mi < 4; ++mi){
      A1f[mi][0] = ldfrag((const u16t*)(sbb + bo + aoff + (4 + mi) * 2048 + c0));
      A1f[mi][1] = ldfrag((const u16t*)(sbb + bo + aoff + (4 + mi) * 2048 + (c0 ^ 64)));
    }
    if (t + 2 < NT){ STA(0,0,bsel,t+2); STA(0,1,bsel,t+2); }
    __builtin_amdgcn_s_barrier();
    asm volatile("s_waitcnt lgkmcnt(0)" ::: "memory");
    __builtin_amdgcn_sched_barrier(0);
    __builtin_amdgcn_s_setprio(1);
#pragma unroll
    for (int mi = 0; mi < 4; ++mi)
#pragma unroll
      for (int ni = 0; ni < 2; ++ni){
        acc[4+mi][ni] = MFMA16(A1f[mi][0], Bf0[ni][0], acc[4+mi][ni], 0, 0, 0);
        acc[4+mi][ni] = MFMA16(A1f[mi][1], Bf0[ni][1], acc[4+mi][ni], 0, 0, 0);
      }
    __builtin_amdgcn_s_setprio(0);
    __builtin_amdgcn_sched_barrier(0);
    __builtin_amdgcn_s_barrier();

    // ---------- phase 3: read B1 (4 reads); MFMA quadrant (A0,B1);
    //            stage (t+2).A1 -> cur buf (A1 region free after ph2)
#pragma unroll
    for (int ni = 0; ni < 2; ++ni){
      Bf1[ni][0] = ldfrag((const u16t*)(sbb + bo + boff + (2 + ni) * 2048 + c0));
      Bf1[ni][1] = ldfrag((const u16t*)(sbb + bo + boff + (2 + ni) * 2048 + (c0 ^ 64)));
    }
    if (t + 2 < NT){ STA(1,0,bsel,t+2); STA(1,1,bsel,t+2); }
    __builtin_amdgcn_s_barrier();
    asm volatile("s_waitcnt lgkmcnt(0)" ::: "memory");
    __builtin_amdgcn_sched_barrier(0);
    __builtin_amdgcn_s_setprio(1);
#pragma unroll
    for (int mi = 0; mi < 4; ++mi)
#pragma unroll
      for (int ni = 0; ni < 2; ++ni){
        acc[mi][2+ni] = MFMA16(A0f[mi][0], Bf1[ni][0], acc[mi][2+ni], 0, 0, 0);
        acc[mi][2+ni] = MFMA16(A0f[mi][1], Bf1[ni][1], acc[mi][2+ni], 0, 0, 0);
      }
    __builtin_amdgcn_s_setprio(0);
    __builtin_amdgcn_sched_barrier(0);
    __builtin_amdgcn_s_barrier();

    // ---------- phase 4: no reads; MFMA quadrant (A1,B1);
    //            stage (t+2).B0 -> cur buf (B0 region free after ph1); vmcnt
    if (t + 2 < NT){ STB(0,0,bsel,t+2); STB(0,1,bsel,t+2); }
    __builtin_amdgcn_s_barrier();
    __builtin_amdgcn_s_setprio(1);
#pragma unroll
    for (int mi = 0; mi < 4; ++mi)
#pragma unroll
      for (int ni = 0; ni < 2; ++ni){
        acc[4+mi][2+ni] = MFMA16(A1f[mi][0], Bf1[ni][0], acc[4+mi][2+ni], 0, 0, 0);
        acc[4+mi][2+ni] = MFMA16(A1f[mi][1], Bf1[ni][1], acc[4+mi][2+ni], 0, 0, 0);
      }
    __builtin_amdgcn_s_setprio(0);
    __builtin_amdgcn_sched_barrier(0);
    if (t + 2 < NT) asm volatile("s_waitcnt vmcnt(6)" ::: "memory");
    else            asm volatile("s_waitcnt vmcnt(0)" ::: "memory");
    __builtin_amdgcn_sched_barrier(0);
    __builtin_amdgcn_s_barrier();
  }

  // ---- epilogue: C/D layout col=lane&15, row=quad*4+reg (verified mapping)
#pragma unroll
  for (int mi = 0; mi < 8; ++mi)
#pragma unroll
    for (int ni = 0; ni < 4; ++ni)
#pragma unroll
      for (int r = 0; r < 4; ++r){
        int row = m0 + wr * 128 + mi * 16 + quad * 4 + r;
        int col = n0 + wc * 64 + ni * 16 + lrow;
        float v = acc[mi][ni][r];
        if (OUT_BF16) ((u16t*)Cv)[(size_t)row * N + col] = f2b(v);
        else          ((float*)Cv)[(size_t)row * N + col] = v;
      }
#undef STA
#undef STB
}

// ---------------------------------------------------------------- RoPE + layout
__global__ __launch_bounds__(256)
void rope_qk(const u16t* __restrict__ qkvb, const float* __restrict__ cosp,
             const float* __restrict__ sinp, u16t* __restrict__ qr, u16t* __restrict__ kr)
{
  const int row = blockIdx.x;            // b*2048 + t
  const int b = row >> 11, t = row & 2047;
  const u16t* src = qkvb + (size_t)row * 6144;
  for (int p = threadIdx.x; p < 2560; p += 256){
    u32t both = *(const u32t*)(src + 2 * p);
    float t0 = b2f((u16t)(both & 0xffff));
    float t1 = b2f((u16t)(both >> 16));
    int j = p & 63;
    float c = cosp[t * 64 + j], s = sinp[t * 64 + j];
    float o0 = t0 * c - t1 * s;
    float o1 = t0 * s + t1 * c;
    u32t packed = cvtpk(o0, o1);
    if (p < 2048){
      int h = p >> 6;
      *(u32t*)(qr + (((size_t)(b * 32 + h) * 2048 + t) * 128 + 2 * j)) = packed;
    } else {
      int kh = (p - 2048) >> 6;
      *(u32t*)(kr + (((size_t)(b * 8 + kh) * 2048 + t) * 128 + 2 * j)) = packed;
    }
  }
}

// ---------------------------------------------------------------- V transpose
__global__ __launch_bounds__(256)
void vtrans(const u16t* __restrict__ qkvb, u16t* __restrict__ vt)
{
  __shared__ u16t sV[64 * 128];
  const int tid = threadIdx.x;
  const int blk = blockIdx.x;                 // (b, kvh, tile)
  const int tile = blk & 31, kvh = (blk >> 5) & 7, b = blk >> 8;
  const int t0 = tile * 64;
  const size_t srcbase = (size_t)(b * 2048 + t0) * 6144 + 5120 + kvh * 128;
#pragma unroll
  for (int it = 0; it < 4; ++it){
    int task = it * 256 + tid;
    int rrow = task >> 4, cb = task & 15;
    *(u16x8*)&sV[rrow * 128 + cb * 8] =
        *(const u16x8*)(qkvb + srcbase + (size_t)rrow * 6144 + cb * 8);
  }
  __syncthreads();
  const size_t dstbase = (size_t)((b * 8 + kvh) * 128) * 2048 + t0;
#pragma unroll
  for (int it = 0; it < 4; ++it){
    int task = it * 256 + tid;
    int tc = task & 7, d = task >> 3;
    u16x8 v;
#pragma unroll
    for (int j = 0; j < 8; ++j) v[j] = sV[(tc * 8 + j) * 128 + d];
    *(u16x8*)(vt + dstbase + (size_t)d * 2048 + tc * 8) = v;
  }
}

// ---------------------------------------------------------------- flash attention v2
// Q (B,32,T,128), K (B,8,T,128), Vt (B,8,128,T) bf16 -> Y (B,T,32*128) bf16.
// Round-6 proven structure (best total 772): 64 q-rows/block, 4 waves x 16
// rows, Q in registers, K/V double-buffered with counted vmcnt(8) (HBM latency
// hidden under prev tile's compute; no __syncthreads in loop).
// Round-8 additions (attn is softmax-VALU-bound: VALUBusy 32% vs MfmaUtil 12%):
//  - cvt_pk P-conversion: v_cvt_pk_bf16_f32 replaces manual f2b (~4 VALU/elem
//    -> 0.5 instr/elem, same RNE rounding => bit-identical output).
//  - defer-max (T13, THR=8): skip alpha exp + 32 o-rescale mults when no row's
//    tile-max exceeds the running max by >8 (log2 domain; P bounded by 2^8 --
//    safe in bf16). Wave-uniform branch via __any.
// LDS: K dbuf 2x16K + V dbuf 2x16K + P 9K = 73 KB -> 2 blocks/CU.
__global__ __launch_bounds__(256)
void attn_fwd(const u16t* __restrict__ Qg, const u16t* __restrict__ Kg,
              const u16t* __restrict__ Vt, u16t* __restrict__ Y)
{
  __shared__ u16t smem[37376];         // 73 KB
  // bytes: K buf0 [0,16K) buf1 [16K,32K); V buf0 [32K,48K) buf1 [48K,64K); P [64K,73K)
  u16t* sP = smem + 32768;             // [q:64] stride 72 u16

  const int tid  = threadIdx.x;
  const int wave = tid >> 6, lane = tid & 63;
  const int lrow = lane & 15, quad = lane >> 4;
  const int qt = 31 - (int)blockIdx.y;     // longest blocks dispatch first
  const int q0 = qt * 64;
  const int bh = blockIdx.x;
  const int b = bh >> 5, h = bh & 31, kvh = h >> 2;
  const float qscale = 0.088388347648318447f * 1.4426950408889634f; // 1/sqrt(128)*log2(e)

  // Q fragments straight from global (once per block)
  bf16x8 aq[4];
  const size_t qbase = ((size_t)bh * 2048 + q0 + wave * 16) * 128;
#pragma unroll
  for (int kk = 0; kk < 4; ++kk)
    aq[kk] = ldfrag(Qg + qbase + (size_t)lrow * 128 + (kk * 4 + quad) * 8);

  const size_t kbase = ((size_t)(b * 8 + kvh) * 2048) * 128;
  const size_t vbase = ((size_t)(b * 8 + kvh) * 128) * 2048;

  // stage K/V tile kt_ into buffer bs_ (8 async16 per wave)
#define STAGEKV(kt_, bs_) {                                                     \
    const int k0_ = (kt_) * 64;                                                 \
    char* dK = (char*)smem + (bs_) * 16384;                                     \
    char* dV = (char*)smem + 32768 + (bs_) * 16384;                             \
    _Pragma("unroll")                                                           \
    for (int r = 0; r < 4; ++r){                                                \
      const int dc = r * 4 + wave;                                              \
      async16(Kg + kbase + (size_t)(k0_ + lane) * 128 + dc * 8, dK + dc * 1024);\
    }                                                                           \
    _Pragma("unroll")                                                           \
    for (int r = 0; r < 4; ++r){                                                \
      const int kvc = r * 2 + (wave >> 1);                                      \
      const int dd  = (wave & 1) * 64 + lane;                                   \
      async16(Vt + vbase + (size_t)dd * 2048 + k0_ + kvc * 8,                   \
              dV + kvc * 2048 + (wave & 1) * 1024);                             \
    } }

  float mi[4] = {-1e30f, -1e30f, -1e30f, -1e30f};
  float li[4] = {0.f, 0.f, 0.f, 0.f};
  floatx4 o[8] = {};
  const int qrow_base = q0 + wave * 16 + quad * 4;
  const int ktiles = qt + 1;

  STAGEKV(0, 0);                       // prologue

  for (int kt = 0; kt < ktiles; ++kt){
    const int bsel = kt & 1;
    const int k0 = kt * 64;
    if (kt + 1 < ktiles){
      STAGEKV(kt + 1, bsel ^ 1);       // prefetch next tile into other buffer
      asm volatile("s_waitcnt vmcnt(8)" ::: "memory");   // tile kt landed
    } else {
      asm volatile("s_waitcnt vmcnt(0)" ::: "memory");
    }
    __builtin_amdgcn_sched_barrier(0);
    __builtin_amdgcn_s_barrier();      // all waves' tile-kt loads landed

    const u16t* cK = smem + bsel * 8192;
    const u16t* cV = smem + 16384 + bsel * 8192;

    // S = Q K^T
    floatx4 s[4] = {};
    __builtin_amdgcn_s_setprio(1);
#pragma unroll
    for (int kk = 0; kk < 4; ++kk){
#pragma unroll
      for (int nt = 0; nt < 4; ++nt){
        bf16x8 bk = ldfrag(&cK[((kk * 4 + quad) * 64 + nt * 16 + lrow) * 8]);
        s[nt] = __builtin_amdgcn_mfma_f32_16x16x32_bf16(aq[kk], bk, s[nt], 0, 0, 0);
      }
    }
    __builtin_amdgcn_s_setprio(0);

    // scale (+ causal mask on the diagonal tile)
    float tt[4][4];
#pragma unroll
    for (int nt = 0; nt < 4; ++nt)
#pragma unroll
      for (int r = 0; r < 4; ++r)
        tt[nt][r] = s[nt][r] * qscale;
    if (kt == ktiles - 1){
#pragma unroll
      for (int nt = 0; nt < 4; ++nt){
        int kc = k0 + nt * 16 + lrow;
#pragma unroll
        for (int r = 0; r < 4; ++r)
          if (kc > qrow_base + r) tt[nt][r] = -1e30f;
      }
    }

    // row max over 64 cols (cols live across lrow lanes)
    float rmax[4];
#pragma unroll
    for (int r = 0; r < 4; ++r)
      rmax[r] = fmaxf(fmaxf(tt[0][r], tt[1][r]), fmaxf(tt[2][r], tt[3][r]));
#pragma unroll
    for (int off = 1; off < 16; off <<= 1){
#pragma unroll
      for (int r = 0; r < 4; ++r)
        rmax[r] = fmaxf(rmax[r], __shfl_xor(rmax[r], off, 64));
    }
    // defer-max: only rescale when some row's max grew past mi+8 (log2 units).
    // When deferred, P = exp2(tt - mi) <= 2^8 -- safe in bf16; li/o unscaled.
    bool grow = (rmax[0] > mi[0] + 8.f) | (rmax[1] > mi[1] + 8.f) |
                (rmax[2] > mi[2] + 8.f) | (rmax[3] > mi[3] + 8.f);
    if (__any(grow)){
      float alpha[4];
#pragma unroll
      for (int r = 0; r < 4; ++r){
        float mn = fmaxf(mi[r], rmax[r]);
        alpha[r] = __builtin_amdgcn_exp2f(mi[r] - mn);
        mi[r] = mn;
        li[r] *= alpha[r];
      }
#pragma unroll
      for (int nt = 0; nt < 8; ++nt){
        o[nt][0] *= alpha[0]; o[nt][1] *= alpha[1];
        o[nt][2] *= alpha[2]; o[nt][3] *= alpha[3];
      }
    }
    float ev[4][4];
    float lsum[4] = {0.f, 0.f, 0.f, 0.f};
#pragma unroll
    for (int nt = 0; nt < 4; ++nt)
#pragma unroll
      for (int r = 0; r < 4; ++r){
        float e = __builtin_amdgcn_exp2f(tt[nt][r] - mi[r]);
        ev[nt][r] = e;
        lsum[r] += e;
      }
    // P -> bf16 via packed cvt (2 elems/instr, RNE identical to f2b)
#pragma unroll
    for (int nt = 0; nt < 4; ++nt){
#pragma unroll
      for (int rp = 0; rp < 4; rp += 2){
        u32t pk = cvtpk(ev[nt][rp], ev[nt][rp + 1]);
        sP[(wave * 16 + quad * 4 + rp) * 72 + nt * 16 + lrow]     = (u16t)pk;
        sP[(wave * 16 + quad * 4 + rp + 1) * 72 + nt * 16 + lrow] = (u16t)(pk >> 16);
      }
    }
#pragma unroll
    for (int off = 1; off < 16; off <<= 1){
#pragma unroll
      for (int r = 0; r < 4; ++r)
        lsum[r] += __shfl_xor(lsum[r], off, 64);
    }
#pragma unroll
    for (int r = 0; r < 4; ++r) li[r] += lsum[r];
    // no barrier needed: each wave reads back only its own sP rows (same-wave
    // LDS RAW is ordered by the DS pipe / lgkmcnt)

    // O += P V
    __builtin_amdgcn_s_setprio(1);
#pragma unroll
    for (int kk = 0; kk < 2; ++kk){
      bf16x8 ap = ldfrag(&sP[(wave * 16 + lrow) * 72 + kk * 32 + quad * 8]);
#pragma unroll
      for (int nt = 0; nt < 8; ++nt){
        bf16x8 bv = ldfrag(&cV[((kk * 4 + quad) * 128 + nt * 16 + lrow) * 8]);
        o[nt] = __builtin_amdgcn_mfma_f32_16x16x32_bf16(ap, bv, o[nt], 0, 0, 0);
      }
    }
    __builtin_amdgcn_s_setprio(0);
    __builtin_amdgcn_sched_barrier(0);
    __builtin_amdgcn_s_barrier();      // buf[bsel] reads done; safe to restage next iter
  }
#undef STAGEKV

  // epilogue: O/l -> Y (B,T,4096)
#pragma unroll
  for (int r = 0; r < 4; ++r){
    int t = q0 + wave * 16 + quad * 4 + r;
    float inv = 1.0f / li[r];
    size_t ybase = ((size_t)(b * 2048 + t)) * 4096 + h * 128;
#pragma unroll
    for (int nt = 0; nt < 8; ++nt)
      Y[ybase + nt * 16 + lrow] = f2b(o[nt][r] * inv);
  }
}

// ---------------------------------------------------------------- launch
extern "C" void kernel_launch(void* const* d_in, const int* in_sizes, int n_in,
                              void* d_out, int out_size, void* d_ws, size_t ws_size,
                              hipStream_t stream)
{
  (void)in_sizes; (void)n_in; (void)out_size; (void)ws_size;
  const float* x    = (const float*)d_in[0];   // (2,2048,4096)
  const float* fc   = (const float*)d_in[1];   // (2048,64)
  const float* fs   = (const float*)d_in[2];   // (2048,64)
  const float* wqkv = (const float*)d_in[3];   // (6144,4096)
  const float* wo   = (const float*)d_in[4];   // (4096,4096)
  float* out = (float*)d_out;                  // (2,2048,4096) f32

  char* ws = (char*)d_ws;
  u16t* xb    = (u16t*)(ws);                    // 32 MiB (reused as yb after gemm1)
  u16t* wqkvb = (u16t*)(ws + 33554432);         // 48 MiB
  u16t* wob   = (u16t*)(ws + 83886080);         // 32 MiB
  u16t* qkvb  = (u16t*)(ws + 117440512);        // 48 MiB
  u16t* qr    = (u16t*)(ws + 167772160);        // 32 MiB
  u16t* kr    = (u16t*)(ws + 201326592);        //  8 MiB
  u16t* vt    = (u16t*)(ws + 209715200);        //  8 MiB  (total 208 MiB)
  u16t* yb    = xb;                             // alias: x dead after gemm1

  cvt_f32_bf16<<<4096, 256, 0, stream>>>(x,    xb,    16777216 / 4);
  cvt_f32_bf16<<<4096, 256, 0, stream>>>(wqkv, wqkvb, 25165824 / 4);
  cvt_f32_bf16<<<4096, 256, 0, stream>>>(wo,   wob,   16777216 / 4);
  gemm256<1><<<dim3(24, 16), 512, 0, stream>>>(xb, wqkvb, qkvb, 4096, 6144, 4096);
  rope_qk<<<4096, 256, 0, stream>>>(qkvb, fc, fs, qr, kr);
  vtrans<<<512, 256, 0, stream>>>(qkvb, vt);
  attn_fwd<<<dim3(64, 32), 256, 0, stream>>>(qr, kr, vt, yb);
  gemm256<0><<<dim3(16, 16), 512, 0, stream>>>(yb, wob, out, 4096, 4096, 4096);
}

// Round 9
// 740.299 us; speedup vs baseline: 1.1270x; 1.0715x over previous
//
#include <hip/hip_runtime.h>

typedef unsigned short u16t;
typedef unsigned int   u32t;
typedef __attribute__((ext_vector_type(8))) __bf16          bf16x8;
typedef __attribute__((ext_vector_type(8))) unsigned short  u16x8;
typedef __attribute__((ext_vector_type(4))) unsigned short  u16x4;
typedef __attribute__((ext_vector_type(4))) float           floatx4;

// f32 -> bf16 round-to-nearest-even (no NaN inputs in this problem)
__device__ __forceinline__ u16t f2b(float f){
  u32t u = __builtin_bit_cast(u32t, f);
  u += 0x7fffu + ((u >> 16) & 1u);
  return (u16t)(u >> 16);
}
__device__ __forceinline__ float b2f(u16t h){
  return __builtin_bit_cast(float, (u32t)h << 16);
}
// async global->LDS, 16B per lane. lds ptr must be wave-uniform (HW adds lane*16).
__device__ __forceinline__ void async16(const void* g, void* l){
  __builtin_amdgcn_global_load_lds((__attribute__((address_space(1))) void*)g,
                                   (__attribute__((address_space(3))) void*)l, 16, 0, 0);
}
__device__ __forceinline__ bf16x8 ldfrag(const u16t* p){
  return __builtin_bit_cast(bf16x8, *(const u16x8*)p);
}

// ---------------------------------------------------------------- cvt f32->bf16
__global__ __launch_bounds__(256)
void cvt_f32_bf16(const float* __restrict__ in, u16t* __restrict__ out, int n4){
  typedef __attribute__((ext_vector_type(4))) float f32x4;
  const f32x4* in4 = (const f32x4*)in;
  int stride = gridDim.x * blockDim.x;
  for (int i = blockIdx.x * blockDim.x + threadIdx.x; i < n4; i += stride){
    f32x4 v = in4[i];
    u16x4 o; o[0]=f2b(v[0]); o[1]=f2b(v[1]); o[2]=f2b(v[2]); o[3]=f2b(v[3]);
    *(u16x4*)(out + (size_t)i * 4) = o;
  }
}

#define MFMA16 __builtin_amdgcn_mfma_f32_16x16x32_bf16

// ---------------------------------------------------------------- GEMM C = A * B^T (BN=256)
// 256x256 tile, BK=64, 8 waves (2M x 4N), 128 KiB double-buffered LDS.
// Round-2 proven schedule: 4 phases per K-tile (12/8/4/0 fragment reads),
// 1 half-tile global_load_lds prefetch per phase, counted vmcnt(6) per K-tile.
// Used for the WO gemm (256 blocks = exactly 1 dispatch round).
template<int OUT_BF16>
__global__ __launch_bounds__(512, 2)
void gemm256(const u16t* __restrict__ A, const u16t* __restrict__ B,
             void* __restrict__ Cv, int M, int N, int K)
{
  (void)M;
  __shared__ u16t smem[65536];              // bytes: A [0,64K), B [64K,128K)
  const int tid  = threadIdx.x;
  const int w    = tid >> 6, lane = tid & 63;
  const int lrow = lane & 15, quad = lane >> 4;
  const int wr   = w >> 2,  wc = w & 3;

  // bijective XCD-aware workgroup swizzle (m204)
  const int nwg  = (int)(gridDim.x * gridDim.y);
  const int flat = (int)(blockIdx.y * gridDim.x + blockIdx.x);
  const int q8 = nwg >> 3, r8 = nwg & 7, xcd = flat & 7, idx = flat >> 3;
  const int wg = (xcd < r8 ? xcd * (q8 + 1) : r8 * (q8 + 1) + (xcd - r8) * q8) + idx;
  const int m0 = (wg / (int)gridDim.x) * 256;
  const int n0 = (wg % (int)gridDim.x) * 256;

  const int srow = lane >> 3;                    // 0..7  (row within 8-row strip)
  const int scol = ((lane & 7) ^ srow) * 8;      // inverse-swizzled k element
  const u16t* gA = A + (size_t)(m0 + w * 8 + srow) * K + scol;
  const u16t* gB = B + (size_t)(n0 + w * 8 + srow) * K + scol;
  char* const ldsA = (char*)smem + w * 1024;
  char* const ldsB = (char*)smem + 65536 + w * 1024;
#define STA(h, i, buf, kt) async16(gA + (size_t)((h)*128 + (i)*64) * K + (kt)*64, \
                                   ldsA + (buf)*32768 + ((h)*2+(i))*8192)
#define STB(h, i, buf, kt) async16(gB + (size_t)((h)*128 + (i)*64) * K + (kt)*64, \
                                   ldsB + (buf)*32768 + ((h)*2+(i))*8192)

  const char* const sbb = (const char*)smem;
  const int c0   = ((quad ^ (lrow & 7)) * 16);       // ks=0 chunk; ks=1 = c0^64
  const int aoff = (wr * 128 + lrow) * 128;          // + mi*2048 + chunk
  const int boff = 65536 + (wc * 64 + lrow) * 128;   // + ni*2048 + chunk

  floatx4 acc[8][4] = {};
  bf16x8 A0f[4][2], A1f[4][2], Bf0[2][2], Bf1[2][2];
  const int NT = K >> 6;

  // ---- prologue: tile0 {A0,A1,B0,B1} -> buf0, tile1 {A0,A1,B0} -> buf1
  STA(0,0,0,0); STA(0,1,0,0); STA(1,0,0,0); STA(1,1,0,0);
  STB(0,0,0,0); STB(0,1,0,0); STB(1,0,0,0); STB(1,1,0,0);
  STA(0,0,1,1); STA(0,1,1,1); STA(1,0,1,1); STA(1,1,1,1);
  STB(0,0,1,1); STB(0,1,1,1);
  asm volatile("s_waitcnt vmcnt(6)" ::: "memory");   // tile0 fully landed
  __builtin_amdgcn_sched_barrier(0);
  __builtin_amdgcn_s_barrier();

  for (int t = 0; t < NT; ++t){
    const int bsel = t & 1, nb = bsel ^ 1;
    const int bo = bsel * 32768;

    // ---------- phase 1: read A0 + B0 (12); MFMA (A0,B0); stage (t+1).B1 -> other buf
#pragma unroll
    for (int mi = 0; mi < 4; ++mi){
      A0f[mi][0] = ldfrag((const u16t*)(sbb + bo + aoff + mi * 2048 + c0));
      A0f[mi][1] = ldfrag((const u16t*)(sbb + bo + aoff + mi * 2048 + (c0 ^ 64)));
    }
#pragma unroll
    for (int ni = 0; ni < 2; ++ni){
      Bf0[ni][0] = ldfrag((const u16t*)(sbb + bo + boff + ni * 2048 + c0));
      Bf0[ni][1] = ldfrag((const u16t*)(sbb + bo + boff + ni * 2048 + (c0 ^ 64)));
    }
    if (t + 1 < NT){ STB(1,0,nb,t+1); STB(1,1,nb,t+1); }
    __builtin_amdgcn_s_barrier();
    asm volatile("s_waitcnt lgkmcnt(0)" ::: "memory");
    __builtin_amdgcn_sched_barrier(0);
    __builtin_amdgcn_s_setprio(1);
#pragma unroll
    for (int mi = 0; mi < 4; ++mi)
#pragma unroll
      for (int ni = 0; ni < 2; ++ni){
        acc[mi][ni] = MFMA16(A0f[mi][0], Bf0[ni][0], acc[mi][ni], 0, 0, 0);
        acc[mi][ni] = MFMA16(A0f[mi][1], Bf0[ni][1], acc[mi][ni], 0, 0, 0);
      }
    __builtin_amdgcn_s_setprio(0);
    __builtin_amdgcn_sched_barrier(0);
    __builtin_amdgcn_s_barrier();

    // ---------- phase 2: read A1 (8); MFMA (A1,B0); stage (t+2).A0 -> cur buf
#pragma unroll
    for (int mi = 0; mi < 4; ++mi){
      A1f[mi][0] = ldfrag((const u16t*)(sbb + bo + aoff + (4 + mi) * 2048 + c0));
      A1f[mi][1] = ldfrag((const u16t*)(sbb + bo + aoff + (4 + mi) * 2048 + (c0 ^ 64)));
    }
    if (t + 2 < NT){ STA(0,0,bsel,t+2); STA(0,1,bsel,t+2); }
    __builtin_amdgcn_s_barrier();
    asm volatile("s_waitcnt lgkmcnt(0)" ::: "memory");
    __builtin_amdgcn_sched_barrier(0);
    __builtin_amdgcn_s_setprio(1);
#pragma unroll
    for (int mi = 0; mi < 4; ++mi)
#pragma unroll
      for (int ni = 0; ni < 2; ++ni){
        acc[4+mi][ni] = MFMA16(A1f[mi][0], Bf0[ni][0], acc[4+mi][ni], 0, 0, 0);
        acc[4+mi][ni] = MFMA16(A1f[mi][1], Bf0[ni][1], acc[4+mi][ni], 0, 0, 0);
      }
    __builtin_amdgcn_s_setprio(0);
    __builtin_amdgcn_sched_barrier(0);
    __builtin_amdgcn_s_barrier();

    // ---------- phase 3: read B1 (4); MFMA (A0,B1); stage (t+2).A1 -> cur buf
#pragma unroll
    for (int ni = 0; ni < 2; ++ni){
      Bf1[ni][0] = ldfrag((const u16t*)(sbb + bo + boff + (2 + ni) * 2048 + c0));
      Bf1[ni][1] = ldfrag((const u16t*)(sbb + bo + boff + (2 + ni) * 2048 + (c0 ^ 64)));
    }
    if (t + 2 < NT){ STA(1,0,bsel,t+2); STA(1,1,bsel,t+2); }
    __builtin_amdgcn_s_barrier();
    asm volatile("s_waitcnt lgkmcnt(0)" ::: "memory");
    __builtin_amdgcn_sched_barrier(0);
    __builtin_amdgcn_s_setprio(1);
#pragma unroll
    for (int mi = 0; mi < 4; ++mi)
#pragma unroll
      for (int ni = 0; ni < 2; ++ni){
        acc[mi][2+ni] = MFMA16(A0f[mi][0], Bf1[ni][0], acc[mi][2+ni], 0, 0, 0);
        acc[mi][2+ni] = MFMA16(A0f[mi][1], Bf1[ni][1], acc[mi][2+ni], 0, 0, 0);
      }
    __builtin_amdgcn_s_setprio(0);
    __builtin_amdgcn_sched_barrier(0);
    __builtin_amdgcn_s_barrier();

    // ---------- phase 4: MFMA (A1,B1); stage (t+2).B0 -> cur buf; vmcnt
    if (t + 2 < NT){ STB(0,0,bsel,t+2); STB(0,1,bsel,t+2); }
    __builtin_amdgcn_s_barrier();
    __builtin_amdgcn_s_setprio(1);
#pragma unroll
    for (int mi = 0; mi < 4; ++mi)
#pragma unroll
      for (int ni = 0; ni < 2; ++ni){
        acc[4+mi][2+ni] = MFMA16(A1f[mi][0], Bf1[ni][0], acc[4+mi][2+ni], 0, 0, 0);
        acc[4+mi][2+ni] = MFMA16(A1f[mi][1], Bf1[ni][1], acc[4+mi][2+ni], 0, 0, 0);
      }
    __builtin_amdgcn_s_setprio(0);
    __builtin_amdgcn_sched_barrier(0);
    if (t + 2 < NT) asm volatile("s_waitcnt vmcnt(6)" ::: "memory");
    else            asm volatile("s_waitcnt vmcnt(0)" ::: "memory");
    __builtin_amdgcn_sched_barrier(0);
    __builtin_amdgcn_s_barrier();
  }

  // ---- epilogue: C/D layout col=lane&15, row=quad*4+reg (verified mapping)
#pragma unroll
  for (int mi = 0; mi < 8; ++mi)
#pragma unroll
    for (int ni = 0; ni < 4; ++ni)
#pragma unroll
      for (int r = 0; r < 4; ++r){
        int row = m0 + wr * 128 + mi * 16 + quad * 4 + r;
        int col = n0 + wc * 64 + ni * 16 + lrow;
        float v = acc[mi][ni][r];
        if (OUT_BF16) ((u16t*)Cv)[(size_t)row * N + col] = f2b(v);
        else          ((float*)Cv)[(size_t)row * N + col] = v;
      }
#undef STA
#undef STB
}

// ---------------------------------------------------------------- GEMM C = A * B^T (BN=192, QKV)
// Same proven 4-phase schedule, tile 256x192 so the QKV grid is 32x16 = 512
// blocks = EXACTLY 2 full dispatch rounds at 1 block/CU (the 256-tile version
// ran 384 blocks = 1.5 rounds, wasting ~25% in the half-empty tail round).
// Per-wave 128x48 (acc[8][3]); B = 3 chunks of 64 rows (24 KB/buf; LDS 112 KB).
// Region-free windows (B wc-strips straddle chunk boundaries => every B chunk
// may be read as late as ph3): stage ph1 <- (t+1).B2 (other buf, last read
// prev-iter ph3), ph2 <- (t+2).A0 (A0 free after ph1), ph3 <- (t+2).A1 (free
// after ph2), ph4 <- (t+2).B0,B1 (all B reads done at ph3's lgkmcnt+barrier).
// 7 issues/tile; at ph4 the 6 newer outstanding are (t+2).{A0,A1,B0,B1} =>
// vmcnt(6) guarantees tile t+1 (incl. its B2 from this iter's ph1) landed.
__global__ __launch_bounds__(512, 2)
void gemm192(const u16t* __restrict__ A, const u16t* __restrict__ B,
             u16t* __restrict__ C, int M, int N, int K)
{
  (void)M;
  __shared__ u16t smem[57344];              // bytes: A [0,64K), B [64K,112K)
  const int tid  = threadIdx.x;
  const int w    = tid >> 6, lane = tid & 63;
  const int lrow = lane & 15, quad = lane >> 4;
  const int wr   = w >> 2,  wc = w & 3;

  // bijective XCD-aware workgroup swizzle (m204); nwg=512 divisible by 8
  const int nwg  = (int)(gridDim.x * gridDim.y);
  const int flat = (int)(blockIdx.y * gridDim.x + blockIdx.x);
  const int q8 = nwg >> 3, r8 = nwg & 7, xcd = flat & 7, idx = flat >> 3;
  const int wg = (xcd < r8 ? xcd * (q8 + 1) : r8 * (q8 + 1) + (xcd - r8) * q8) + idx;
  const int m0 = (wg / (int)gridDim.x) * 256;
  const int n0 = (wg % (int)gridDim.x) * 192;

  const int srow = lane >> 3;
  const int scol = ((lane & 7) ^ srow) * 8;
  const u16t* gA = A + (size_t)(m0 + w * 8 + srow) * K + scol;
  const u16t* gB = B + (size_t)(n0 + w * 8 + srow) * K + scol;
  char* const ldsA = (char*)smem + w * 1024;
  char* const ldsB = (char*)smem + 65536 + w * 1024;
#define STA(h, i, buf, kt) async16(gA + (size_t)((h)*128 + (i)*64) * K + (kt)*64, \
                                   ldsA + (buf)*32768 + ((h)*2+(i))*8192)
#define STB(c, buf, kt)    async16(gB + (size_t)((c)*64) * K + (kt)*64, \
                                   ldsB + (buf)*24576 + (c)*8192)

  const char* const sbb = (const char*)smem;
  const int c0   = ((quad ^ (lrow & 7)) * 16);
  const int aoff = (wr * 128 + lrow) * 128;          // + bsel*32768 + mi*2048 + chunk
  const int boff = 65536 + (wc * 48 + lrow) * 128;   // + bsel*24576 + ni*2048 + chunk

  floatx4 acc[8][3] = {};
  bf16x8 A0f[4][2], A1f[4][2], Bf0[2][2], Bf1[2];
  const int NT = K >> 6;

  // ---- prologue: tile0 {A0,B0,B1,B2,A1} (7) -> buf0, tile1 {A0,B0,B1,A1} (6) -> buf1
  STA(0,0,0,0); STA(0,1,0,0);
  STB(0,0,0);   STB(1,0,0);   STB(2,0,0);
  STA(1,0,0,0); STA(1,1,0,0);
  STA(0,0,1,1); STA(0,1,1,1);
  STB(0,1,1);   STB(1,1,1);
  STA(1,0,1,1); STA(1,1,1,1);
  asm volatile("s_waitcnt vmcnt(6)" ::: "memory");   // tile0 (first 7) landed
  __builtin_amdgcn_sched_barrier(0);
  __builtin_amdgcn_s_barrier();

  for (int t = 0; t < NT; ++t){
    const int bsel = t & 1, nb = bsel ^ 1;
    const int ao = bsel * 32768, bo = bsel * 24576;

    // ---------- phase 1: read A0 (8) + B0 (4); MFMA (A0,B0) 16; stage (t+1).B2 -> other buf
#pragma unroll
    for (int mi = 0; mi < 4; ++mi){
      A0f[mi][0] = ldfrag((const u16t*)(sbb + ao + aoff + mi * 2048 + c0));
      A0f[mi][1] = ldfrag((const u16t*)(sbb + ao + aoff + mi * 2048 + (c0 ^ 64)));
    }
#pragma unroll
    for (int ni = 0; ni < 2; ++ni){
      Bf0[ni][0] = ldfrag((const u16t*)(sbb + bo + boff + ni * 2048 + c0));
      Bf0[ni][1] = ldfrag((const u16t*)(sbb + bo + boff + ni * 2048 + (c0 ^ 64)));
    }
    if (t + 1 < NT){ STB(2,nb,t+1); }
    __builtin_amdgcn_s_barrier();
    asm volatile("s_waitcnt lgkmcnt(0)" ::: "memory");
    __builtin_amdgcn_sched_barrier(0);
    __builtin_amdgcn_s_setprio(1);
#pragma unroll
    for (int mi = 0; mi < 4; ++mi)
#pragma unroll
      for (int ni = 0; ni < 2; ++ni){
        acc[mi][ni] = MFMA16(A0f[mi][0], Bf0[ni][0], acc[mi][ni], 0, 0, 0);
        acc[mi][ni] = MFMA16(A0f[mi][1], Bf0[ni][1], acc[mi][ni], 0, 0, 0);
      }
    __builtin_amdgcn_s_setprio(0);
    __builtin_amdgcn_sched_barrier(0);
    __builtin_amdgcn_s_barrier();

    // ---------- phase 2: read A1 (8); MFMA (A1,B0) 16; stage (t+2).A0 -> cur buf
#pragma unroll
    for (int mi = 0; mi < 4; ++mi){
      A1f[mi][0] = ldfrag((const u16t*)(sbb + ao + aoff + (4 + mi) * 2048 + c0));
      A1f[mi][1] = ldfrag((const u16t*)(sbb + ao + aoff + (4 + mi) * 2048 + (c0 ^ 64)));
    }
    if (t + 2 < NT){ STA(0,0,bsel,t+2); STA(0,1,bsel,t+2); }
    __builtin_amdgcn_s_barrier();
    asm volatile("s_waitcnt lgkmcnt(0)" ::: "memory");
    __builtin_amdgcn_sched_barrier(0);
    __builtin_amdgcn_s_setprio(1);
#pragma unroll
    for (int mi = 0; mi < 4; ++mi)
#pragma unroll
      for (int ni = 0; ni < 2; ++ni){
        acc[4+mi][ni] = MFMA16(A1f[mi][0], Bf0[ni][0], acc[4+mi][ni], 0, 0, 0);
        acc[4+mi][ni] = MFMA16(A1f[mi][1], Bf0[ni][1], acc[4+mi][ni], 0, 0, 0);
      }
    __builtin_amdgcn_s_setprio(0);
    __builtin_amdgcn_sched_barrier(0);
    __builtin_amdgcn_s_barrier();

    // ---------- phase 3: read B1 (2, ni=2); MFMA (A0,B1) 8; stage (t+2).A1 -> cur buf
    Bf1[0] = ldfrag((const u16t*)(sbb + bo + boff + 2 * 2048 + c0));
    Bf1[1] = ldfrag((const u16t*)(sbb + bo + boff + 2 * 2048 + (c0 ^ 64)));
    if (t + 2 < NT){ STA(1,0,bsel,t+2); STA(1,1,bsel,t+2); }
    __builtin_amdgcn_s_barrier();
    asm volatile("s_waitcnt lgkmcnt(0)" ::: "memory");
    __builtin_amdgcn_sched_barrier(0);
    __builtin_amdgcn_s_setprio(1);
#pragma unroll
    for (int mi = 0; mi < 4; ++mi){
      acc[mi][2] = MFMA16(A0f[mi][0], Bf1[0], acc[mi][2], 0, 0, 0);
      acc[mi][2] = MFMA16(A0f[mi][1], Bf1[1], acc[mi][2], 0, 0, 0);
    }
    __builtin_amdgcn_s_setprio(0);
    __builtin_amdgcn_sched_barrier(0);
    __builtin_amdgcn_s_barrier();

    // ---------- phase 4: MFMA (A1,B1) 8; stage (t+2).B0,B1 -> cur buf; vmcnt
    if (t + 2 < NT){ STB(0,bsel,t+2); STB(1,bsel,t+2); }
    __builtin_amdgcn_s_barrier();
    __builtin_amdgcn_s_setprio(1);
#pragma unroll
    for (int mi = 0; mi < 4; ++mi){
      acc[4+mi][2] = MFMA16(A1f[mi][0], Bf1[0], acc[4+mi][2], 0, 0, 0);
      acc[4+mi][2] = MFMA16(A1f[mi][1], Bf1[1], acc[4+mi][2], 0, 0, 0);
    }
    __builtin_amdgcn_s_setprio(0);
    __builtin_amdgcn_sched_barrier(0);
    if (t + 2 < NT) asm volatile("s_waitcnt vmcnt(6)" ::: "memory");
    else            asm volatile("s_waitcnt vmcnt(0)" ::: "memory");
    __builtin_amdgcn_sched_barrier(0);
    __builtin_amdgcn_s_barrier();
  }

  // ---- epilogue
#pragma unroll
  for (int mi = 0; mi < 8; ++mi)
#pragma unroll
    for (int ni = 0; ni < 3; ++ni)
#pragma unroll
      for (int r = 0; r < 4; ++r){
        int row = m0 + wr * 128 + mi * 16 + quad * 4 + r;
        int col = n0 + wc * 48 + ni * 16 + lrow;
        C[(size_t)row * N + col] = f2b(acc[mi][ni][r]);
      }
#undef STA
#undef STB
}

// ---------------------------------------------------------------- RoPE + layout
__global__ __launch_bounds__(256)
void rope_qk(const u16t* __restrict__ qkvb, const float* __restrict__ cosp,
             const float* __restrict__ sinp, u16t* __restrict__ qr, u16t* __restrict__ kr)
{
  const int row = blockIdx.x;            // b*2048 + t
  const int b = row >> 11, t = row & 2047;
  const u16t* src = qkvb + (size_t)row * 6144;
  for (int p = threadIdx.x; p < 2560; p += 256){
    u32t both = *(const u32t*)(src + 2 * p);
    float t0 = b2f((u16t)(both & 0xffff));
    float t1 = b2f((u16t)(both >> 16));
    int j = p & 63;
    float c = cosp[t * 64 + j], s = sinp[t * 64 + j];
    float o0 = t0 * c - t1 * s;
    float o1 = t0 * s + t1 * c;
    u32t packed = (u32t)f2b(o0) | ((u32t)f2b(o1) << 16);
    if (p < 2048){
      int h = p >> 6;
      *(u32t*)(qr + (((size_t)(b * 32 + h) * 2048 + t) * 128 + 2 * j)) = packed;
    } else {
      int kh = (p - 2048) >> 6;
      *(u32t*)(kr + (((size_t)(b * 8 + kh) * 2048 + t) * 128 + 2 * j)) = packed;
    }
  }
}

// ---------------------------------------------------------------- V transpose
__global__ __launch_bounds__(256)
void vtrans(const u16t* __restrict__ qkvb, u16t* __restrict__ vt)
{
  __shared__ u16t sV[64 * 128];
  const int tid = threadIdx.x;
  const int blk = blockIdx.x;                 // (b, kvh, tile)
  const int tile = blk & 31, kvh = (blk >> 5) & 7, b = blk >> 8;
  const int t0 = tile * 64;
  const size_t srcbase = (size_t)(b * 2048 + t0) * 6144 + 5120 + kvh * 128;
#pragma unroll
  for (int it = 0; it < 4; ++it){
    int task = it * 256 + tid;
    int rrow = task >> 4, cb = task & 15;
    *(u16x8*)&sV[rrow * 128 + cb * 8] =
        *(const u16x8*)(qkvb + srcbase + (size_t)rrow * 6144 + cb * 8);
  }
  __syncthreads();
  const size_t dstbase = (size_t)((b * 8 + kvh) * 128) * 2048 + t0;
#pragma unroll
  for (int it = 0; it < 4; ++it){
    int task = it * 256 + tid;
    int tc = task & 7, d = task >> 3;
    u16x8 v;
#pragma unroll
    for (int j = 0; j < 8; ++j) v[j] = sV[(tc * 8 + j) * 128 + d];
    *(u16x8*)(vt + dstbase + (size_t)d * 2048 + tc * 8) = v;
  }
}

// ---------------------------------------------------------------- flash attention v2
// Round-6 proven version (best total 772 us): 64 q-rows/block, 4 waves x 16
// rows, Q in registers, K/V double-buffered with counted vmcnt(8) (HBM latency
// hidden under prev tile's compute; no __syncthreads in loop).
// LDS: K dbuf 2x16K + V dbuf 2x16K + P 9K = 73 KB -> 2 blocks/CU.
__global__ __launch_bounds__(256)
void attn_fwd(const u16t* __restrict__ Qg, const u16t* __restrict__ Kg,
              const u16t* __restrict__ Vt, u16t* __restrict__ Y)
{
  __shared__ u16t smem[37376];         // 73 KB
  u16t* sP = smem + 32768;             // [q:64] stride 72 u16

  const int tid  = threadIdx.x;
  const int wave = tid >> 6, lane = tid & 63;
  const int lrow = lane & 15, quad = lane >> 4;
  const int qt = 31 - (int)blockIdx.y;     // longest blocks dispatch first
  const int q0 = qt * 64;
  const int bh = blockIdx.x;
  const int b = bh >> 5, h = bh & 31, kvh = h >> 2;
  const float qscale = 0.088388347648318447f * 1.4426950408889634f; // 1/sqrt(128)*log2(e)

  bf16x8 aq[4];
  const size_t qbase = ((size_t)bh * 2048 + q0 + wave * 16) * 128;
#pragma unroll
  for (int kk = 0; kk < 4; ++kk)
    aq[kk] = ldfrag(Qg + qbase + (size_t)lrow * 128 + (kk * 4 + quad) * 8);

  const size_t kbase = ((size_t)(b * 8 + kvh) * 2048) * 128;
  const size_t vbase = ((size_t)(b * 8 + kvh) * 128) * 2048;

#define STAGEKV(kt_, bs_) {                                                     \
    const int k0_ = (kt_) * 64;                                                 \
    char* dK = (char*)smem + (bs_) * 16384;                                     \
    char* dV = (char*)smem + 32768 + (bs_) * 16384;                             \
    _Pragma("unroll")                                                           \
    for (int r = 0; r < 4; ++r){                                                \
      const int dc = r * 4 + wave;                                              \
      async16(Kg + kbase + (size_t)(k0_ + lane) * 128 + dc * 8, dK + dc * 1024);\
    }                                                                           \
    _Pragma("unroll")                                                           \
    for (int r = 0; r < 4; ++r){                                                \
      const int kvc = r * 2 + (wave >> 1);                                      \
      const int dd  = (wave & 1) * 64 + lane;                                   \
      async16(Vt + vbase + (size_t)dd * 2048 + k0_ + kvc * 8,                   \
              dV + kvc * 2048 + (wave & 1) * 1024);                             \
    } }

  float mi[4] = {-1e30f, -1e30f, -1e30f, -1e30f};
  float li[4] = {0.f, 0.f, 0.f, 0.f};
  floatx4 o[8] = {};
  const int qrow_base = q0 + wave * 16 + quad * 4;
  const int ktiles = qt + 1;

  STAGEKV(0, 0);                       // prologue

  for (int kt = 0; kt < ktiles; ++kt){
    const int bsel = kt & 1;
    const int k0 = kt * 64;
    if (kt + 1 < ktiles){
      STAGEKV(kt + 1, bsel ^ 1);       // prefetch next tile into other buffer
      asm volatile("s_waitcnt vmcnt(8)" ::: "memory");   // tile kt landed
    } else {
      asm volatile("s_waitcnt vmcnt(0)" ::: "memory");
    }
    __builtin_amdgcn_sched_barrier(0);
    __builtin_amdgcn_s_barrier();      // all waves' tile-kt loads landed

    const u16t* cK = smem + bsel * 8192;
    const u16t* cV = smem + 16384 + bsel * 8192;

    // S = Q K^T
    floatx4 s[4] = {};
    __builtin_amdgcn_s_setprio(1);
#pragma unroll
    for (int kk = 0; kk < 4; ++kk){
#pragma unroll
      for (int nt = 0; nt < 4; ++nt){
        bf16x8 bk = ldfrag(&cK[((kk * 4 + quad) * 64 + nt * 16 + lrow) * 8]);
        s[nt] = __builtin_amdgcn_mfma_f32_16x16x32_bf16(aq[kk], bk, s[nt], 0, 0, 0);
      }
    }
    __builtin_amdgcn_s_setprio(0);

    // scale (+ causal mask on the diagonal tile)
    float tt[4][4];
#pragma unroll
    for (int nt = 0; nt < 4; ++nt)
#pragma unroll
      for (int r = 0; r < 4; ++r)
        tt[nt][r] = s[nt][r] * qscale;
    if (kt == ktiles - 1){
#pragma unroll
      for (int nt = 0; nt < 4; ++nt){
        int kc = k0 + nt * 16 + lrow;
#pragma unroll
        for (int r = 0; r < 4; ++r)
          if (kc > qrow_base + r) tt[nt][r] = -1e30f;
      }
    }

    // row max over 64 cols (cols live across lrow lanes)
    float rmax[4];
#pragma unroll
    for (int r = 0; r < 4; ++r)
      rmax[r] = fmaxf(fmaxf(tt[0][r], tt[1][r]), fmaxf(tt[2][r], tt[3][r]));
#pragma unroll
    for (int off = 1; off < 16; off <<= 1){
#pragma unroll
      for (int r = 0; r < 4; ++r)
        rmax[r] = fmaxf(rmax[r], __shfl_xor(rmax[r], off, 64));
    }
    float alpha[4];
#pragma unroll
    for (int r = 0; r < 4; ++r){
      float mn = fmaxf(mi[r], rmax[r]);
      alpha[r] = __builtin_amdgcn_exp2f(mi[r] - mn);
      mi[r] = mn;
    }
    float lsum[4] = {0.f, 0.f, 0.f, 0.f};
#pragma unroll
    for (int nt = 0; nt < 4; ++nt)
#pragma unroll
      for (int r = 0; r < 4; ++r){
        float e = __builtin_amdgcn_exp2f(tt[nt][r] - mi[r]);
        lsum[r] += e;
        sP[(wave * 16 + quad * 4 + r) * 72 + nt * 16 + lrow] = f2b(e);
      }
#pragma unroll
    for (int off = 1; off < 16; off <<= 1){
#pragma unroll
      for (int r = 0; r < 4; ++r)
        lsum[r] += __shfl_xor(lsum[r], off, 64);
    }
#pragma unroll
    for (int r = 0; r < 4; ++r) li[r] = li[r] * alpha[r] + lsum[r];
#pragma unroll
    for (int nt = 0; nt < 8; ++nt){
      o[nt][0] *= alpha[0]; o[nt][1] *= alpha[1];
      o[nt][2] *= alpha[2]; o[nt][3] *= alpha[3];
    }
    // no barrier needed: each wave reads back only its own sP rows (same-wave
    // LDS RAW is ordered by the DS pipe / lgkmcnt)

    // O += P V
    __builtin_amdgcn_s_setprio(1);
#pragma unroll
    for (int kk = 0; kk < 2; ++kk){
      bf16x8 ap = ldfrag(&sP[(wave * 16 + lrow) * 72 + kk * 32 + quad * 8]);
#pragma unroll
      for (int nt = 0; nt < 8; ++nt){
        bf16x8 bv = ldfrag(&cV[((kk * 4 + quad) * 128 + nt * 16 + lrow) * 8]);
        o[nt] = __builtin_amdgcn_mfma_f32_16x16x32_bf16(ap, bv, o[nt], 0, 0, 0);
      }
    }
    __builtin_amdgcn_s_setprio(0);
    __builtin_amdgcn_sched_barrier(0);
    __builtin_amdgcn_s_barrier();      // buf[bsel] reads done; safe to restage next iter
  }
#undef STAGEKV

  // epilogue: O/l -> Y (B,T,4096)
#pragma unroll
  for (int r = 0; r < 4; ++r){
    int t = q0 + wave * 16 + quad * 4 + r;
    float inv = 1.0f / li[r];
    size_t ybase = ((size_t)(b * 2048 + t)) * 4096 + h * 128;
#pragma unroll
    for (int nt = 0; nt < 8; ++nt)
      Y[ybase + nt * 16 + lrow] = f2b(o[nt][r] * inv);
  }
}

// ---------------------------------------------------------------- launch
extern "C" void kernel_launch(void* const* d_in, const int* in_sizes, int n_in,
                              void* d_out, int out_size, void* d_ws, size_t ws_size,
                              hipStream_t stream)
{
  (void)in_sizes; (void)n_in; (void)out_size; (void)ws_size;
  const float* x    = (const float*)d_in[0];   // (2,2048,4096)
  const float* fc   = (const float*)d_in[1];   // (2048,64)
  const float* fs   = (const float*)d_in[2];   // (2048,64)
  const float* wqkv = (const float*)d_in[3];   // (6144,4096)
  const float* wo   = (const float*)d_in[4];   // (4096,4096)
  float* out = (float*)d_out;                  // (2,2048,4096) f32

  char* ws = (char*)d_ws;
  u16t* xb    = (u16t*)(ws);                    // 32 MiB (reused as yb after gemm1)
  u16t* wqkvb = (u16t*)(ws + 33554432);         // 48 MiB
  u16t* wob   = (u16t*)(ws + 83886080);         // 32 MiB
  u16t* qkvb  = (u16t*)(ws + 117440512);        // 48 MiB
  u16t* qr    = (u16t*)(ws + 167772160);        // 32 MiB
  u16t* kr    = (u16t*)(ws + 201326592);        //  8 MiB
  u16t* vt    = (u16t*)(ws + 209715200);        //  8 MiB  (total 208 MiB)
  u16t* yb    = xb;                             // alias: x dead after gemm1

  cvt_f32_bf16<<<4096, 256, 0, stream>>>(x,    xb,    16777216 / 4);
  cvt_f32_bf16<<<4096, 256, 0, stream>>>(wqkv, wqkvb, 25165824 / 4);
  cvt_f32_bf16<<<4096, 256, 0, stream>>>(wo,   wob,   16777216 / 4);
  gemm192<<<dim3(32, 16), 512, 0, stream>>>(xb, wqkvb, qkvb, 4096, 6144, 4096);
  rope_qk<<<4096, 256, 0, stream>>>(qkvb, fc, fs, qr, kr);
  vtrans<<<512, 256, 0, stream>>>(qkvb, vt);
  attn_fwd<<<dim3(64, 32), 256, 0, stream>>>(qr, kr, vt, yb);
  gemm256<0><<<dim3(16, 16), 512, 0, stream>>>(yb, wob, out, 4096, 4096, 4096);
}